// Round 7
// baseline (319.209 us; speedup 1.0000x reference)
//
#include <hip/hip_runtime.h>
#include <math.h>

#define NNODES 50000
#define NEDGES 800000

// binned CSR build
#define BIN_SHIFT 9
#define BIN_W 512
#define NBINS 98            // ceil(50000/512)
#define CAP 12288           // per-bin record capacity (mean 8192 + 45 sigma)
#define ATILE 4096          // edges per bin block
#define NBINBLK ((NEDGES + ATILE - 1) / ATILE)   // 196

typedef _Float16 f16;
typedef __attribute__((ext_vector_type(2))) _Float16 f16x2;
typedef __attribute__((ext_vector_type(4))) _Float16 f16x4;
typedef __attribute__((ext_vector_type(8))) _Float16 f16x8;
typedef __attribute__((ext_vector_type(4))) float f32x4;
typedef __attribute__((ext_vector_type(4))) float fv4;

__device__ __forceinline__ float leaky02(float v) { return v > 0.f ? v : 0.2f * v; }

// wave-local LDS visibility (staging is private per half-wave; wave lockstep)
__device__ __forceinline__ void wave_lds_fence() {
  __asm__ volatile("s_waitcnt lgkmcnt(0)" ::: "memory");
}

// non-temporal helpers: stream-once data must not evict the h-table / als / W
// from L2 (the gather's 2nd-touch hits are the only reducible FETCH bytes).
__device__ __forceinline__ int2 ntload_int2(const int2* p) {
  long long v = __builtin_nontemporal_load((const long long*)p);
  int2 r; r.x = (int)(unsigned)(v & 0xffffffffLL); r.y = (int)(v >> 32);
  return r;
}
__device__ __forceinline__ void ntstore_int2(int2* p, int2 v) {
  long long x = ((long long)v.y << 32) | (unsigned)v.x;
  __builtin_nontemporal_store(x, (long long*)p);
}
__device__ __forceinline__ float4 ntload_float4(const float4* p) {
  fv4 v = __builtin_nontemporal_load((const fv4*)p);
  return make_float4(v[0], v[1], v[2], v[3]);
}

// ---------------- phase A: bin edges by dst-range (device body) ----------------

__device__ __forceinline__ void bin_body(int bid,
                                         const int* __restrict__ dst,
                                         const int* __restrict__ src,
                                         const float* __restrict__ ew,
                                         int* __restrict__ binCursor,
                                         int2* __restrict__ binned, int ne) {
  __shared__ int cnt[NBINS];
  __shared__ int gbase[NBINS];
  int tid = threadIdx.x;
  int t0 = bid * ATILE;
  if (tid < NBINS) cnt[tid] = 0;
  __syncthreads();
  int saved[ATILE / 256];
  #pragma unroll
  for (int u = 0; u < ATILE / 256; ++u) {
    int i = t0 + u * 256 + tid;
    int v = 0;
    if (i < ne) {
      int d = __builtin_nontemporal_load(&dst[i]);  // d < 65536 -> 16 bits
      int idx = atomicAdd(&cnt[d >> BIN_SHIFT], 1); // idx < 4096 -> 12 bits
      v = d | (idx << 16);
    }
    saved[u] = v;
  }
  __syncthreads();
  if (tid < NBINS) gbase[tid] = atomicAdd(&binCursor[tid], cnt[tid]);
  __syncthreads();
  #pragma unroll
  for (int u = 0; u < ATILE / 256; ++u) {
    int i = t0 + u * 256 + tid;
    if (i < ne) {
      int v = saved[u];
      int d = v & 0xffff;
      int idx = (int)((unsigned)v >> 16);
      int b = d >> BIN_SHIFT;
      int slot = gbase[b] + idx;
      if (slot < CAP) {                             // statistically never taken
        int s = __builtin_nontemporal_load(&src[i]);
        float w = __builtin_nontemporal_load(&ew[i]);
        ntstore_int2(&binned[(size_t)b * CAP + slot],
                     make_int2(s | (d << 16), __float_as_int(w)));
      }
    }
  }
}

// ---------------- phase B: per-bin CSR finalize ----------------

__global__ __launch_bounds__(256) void build_kernel(const int2* __restrict__ binned,
                                                    const int* __restrict__ binCursor,
                                                    int* __restrict__ offsets,
                                                    int2* __restrict__ edgeSW, int n) {
  __shared__ int sizes[NBINS];
  __shared__ int cnt[BIN_W];
  __shared__ int wsum[4];
  __shared__ int bstartS;
  int tid = threadIdx.x;
  int b = blockIdx.x;
  if (tid < NBINS) sizes[tid] = binCursor[tid];
  cnt[tid] = 0;
  cnt[tid + 256] = 0;
  __syncthreads();
  if (tid == 0) {
    int s = 0;
    for (int k = 0; k < b; ++k) s += (sizes[k] < CAP ? sizes[k] : CAP);
    bstartS = s;
  }
  int mySize = sizes[b];
  if (mySize > CAP) mySize = CAP;
  __syncthreads();
  const int2* mybin = binned + (size_t)b * CAP;
  for (int i = tid; i < mySize; i += 256) {
    int hx = __builtin_nontemporal_load(&mybin[i].x);
    atomicAdd(&cnt[((unsigned)hx >> 16) - b * BIN_W], 1);
  }
  __syncthreads();
  int c0 = cnt[2 * tid], c1 = cnt[2 * tid + 1];
  int s2 = c0 + c1;
  int lane = tid & 63, wid = tid >> 6;
  int incl = s2;
  #pragma unroll
  for (int o = 1; o < 64; o <<= 1) {
    int u = __shfl_up(incl, o, 64);
    if (lane >= o) incl += u;
  }
  if (lane == 63) wsum[wid] = incl;
  __syncthreads();
  if (tid == 0) {
    int r = 0;
    #pragma unroll
    for (int w = 0; w < 4; ++w) { int t = wsum[w]; wsum[w] = r; r += t; }
  }
  __syncthreads();
  int excl0 = bstartS + wsum[wid] + incl - s2;  // global CSR start of node 2*tid
  int excl1 = excl0 + c0;
  int node0 = b * BIN_W;
  if (node0 + 2 * tid < n)     offsets[node0 + 2 * tid]     = excl0;
  if (node0 + 2 * tid + 1 < n) offsets[node0 + 2 * tid + 1] = excl1;
  if (b == NBINS - 1 && tid == 0) offsets[n] = bstartS + mySize;
  __syncthreads();
  cnt[2 * tid] = excl0;                         // becomes the global-position cursor
  cnt[2 * tid + 1] = excl1;
  __syncthreads();
  for (int i = tid; i < mySize; i += 256) {
    int2 r = ntload_int2(&mybin[i]);
    int dloc = (int)((unsigned)r.x >> 16) - b * BIN_W;
    int pos = atomicAdd(&cnt[dloc], 1);
    edgeSW[pos] = make_int2(r.x & 0xffff, r.y);
  }
}

// ---------------- fp16 MFMA GEMM + fused attention-logit epilogue -----------
// 256-thread 4-wave version (layer 1 inside the fused front). Weights are read
// DIRECTLY from the f32 W (layout [K][BN]) with on-the-fly transpose+convert
// during Bs staging — W is 131 KB and L2-resident after the first block, so
// this removes the init/transpose kernel entirely.

template<int BN>
__device__ __forceinline__ void gemm_body(int bid,
                                          const float* __restrict__ A,
                                          const float* __restrict__ W,
                                          f16* __restrict__ C,
                                          const float* __restrict__ a_src,
                                          const float* __restrict__ a_dst,
                                          float* __restrict__ als,
                                          float* __restrict__ ald,
                                          int M, int K) {
  constexpr int BM = 64;
  constexpr int WN = BN / 2;
  constexpr int MT = 2, NT = WN / 16;
  __shared__ f16 As[BM * 72];
  __shared__ f16 Bs[BN * 72];
  int tid = threadIdx.x;
  int lane = tid & 63, wave = tid >> 6;
  int wm = wave & 1, wn = wave >> 1;
  int row0 = bid * BM;
  int quad = lane >> 4, cc = lane & 15;

  f32x4 acc[MT][NT];
  #pragma unroll
  for (int mt = 0; mt < MT; ++mt)
    #pragma unroll
    for (int nt = 0; nt < NT; ++nt)
      acc[mt][nt] = (f32x4){0.f, 0.f, 0.f, 0.f};

  for (int k0 = 0; k0 < K; k0 += 64) {
    __syncthreads();
    #pragma unroll
    for (int i = 0; i < 4; ++i) {
      int r = i * 16 + (tid >> 4);
      int kc = (tid & 15) * 4;
      float4 av = make_float4(0.f, 0.f, 0.f, 0.f);
      if (row0 + r < M) av = ntload_float4((const float4*)&A[(size_t)(row0 + r) * K + k0 + kc]);
      *(f16x4*)&As[r * 72 + kc] = (f16x4){(f16)av.x, (f16)av.y, (f16)av.z, (f16)av.w};
    }
    #pragma unroll
    for (int i = 0; i < BN / 32; ++i) {
      int d = i * 32 + (tid >> 3);
      int kc = (tid & 7) * 8;
      f16x8 wv;
      #pragma unroll
      for (int j = 0; j < 8; ++j) wv[j] = (f16)W[(size_t)(k0 + kc + j) * BN + d];
      *(f16x8*)&Bs[d * 72 + kc] = wv;
    }
    __syncthreads();
    #pragma unroll
    for (int ki = 0; ki < 2; ++ki) {
      f16x8 a[MT], b[NT];
      #pragma unroll
      for (int mt = 0; mt < MT; ++mt)
        a[mt] = *(const f16x8*)&As[(wm * 32 + mt * 16 + cc) * 72 + ki * 32 + quad * 8];
      #pragma unroll
      for (int nt = 0; nt < NT; ++nt)
        b[nt] = *(const f16x8*)&Bs[(wn * WN + nt * 16 + cc) * 72 + ki * 32 + quad * 8];
      #pragma unroll
      for (int mt = 0; mt < MT; ++mt)
        #pragma unroll
        for (int nt = 0; nt < NT; ++nt)
          acc[mt][nt] = __builtin_amdgcn_mfma_f32_16x16x32_f16(a[mt], b[nt], acc[mt][nt], 0, 0, 0);
    }
  }

  float asv[NT], adv[NT];
  #pragma unroll
  for (int nt = 0; nt < NT; ++nt) {
    int ch = wn * WN + nt * 16 + cc;
    asv[nt] = a_src[ch];
    adv[nt] = a_dst[ch];
  }

  #pragma unroll
  for (int mt = 0; mt < MT; ++mt)
    #pragma unroll
    for (int v = 0; v < 4; ++v) {
      int row = row0 + wm * 32 + mt * 16 + quad * 4 + v;
      if (row < M) {
        #pragma unroll
        for (int nt = 0; nt < NT; ++nt)
          C[(size_t)row * BN + wn * WN + nt * 16 + cc] = (f16)acc[mt][nt][v];
      }
      float s0 = acc[mt][0][v] * asv[0] + acc[mt][1][v] * asv[1];
      float s1 = acc[mt][2][v] * asv[2] + acc[mt][3][v] * asv[3];
      float d0 = acc[mt][0][v] * adv[0] + acc[mt][1][v] * adv[1];
      float d1 = acc[mt][2][v] * adv[2] + acc[mt][3][v] * adv[3];
      #pragma unroll
      for (int o = 1; o < 16; o <<= 1) {
        s0 += __shfl_xor(s0, o);
        s1 += __shfl_xor(s1, o);
        d0 += __shfl_xor(d0, o);
        d1 += __shfl_xor(d1, o);
      }
      if (cc == 0 && row < M) {
        *(float2*)&als[row * 4 + 2 * wn] = make_float2(s0, s1);
        *(float2*)&ald[row * 4 + 2 * wn] = make_float2(d0, d1);
      }
    }
}

// ---------------- fused front: bin (196 blocks) || gemm1 (782 blocks) -------

__global__ __launch_bounds__(256) void fused_front_kernel(const int* __restrict__ dst,
                                                          const int* __restrict__ src,
                                                          const float* __restrict__ ew,
                                                          int* __restrict__ binCursor,
                                                          int2* __restrict__ binned, int ne,
                                                          const float* __restrict__ A,
                                                          const float* __restrict__ W,
                                                          f16* __restrict__ C,
                                                          const float* __restrict__ a_src,
                                                          const float* __restrict__ a_dst,
                                                          float* __restrict__ als,
                                                          float* __restrict__ ald,
                                                          int M, int K) {
  if (blockIdx.x < NBINBLK)
    bin_body(blockIdx.x, dst, src, ew, binCursor, binned, ne);
  else
    gemm_body<128>(blockIdx.x - NBINBLK, A, W, C, a_src, a_dst, als, ald, M, K);
}

// ---------------- fused aggregate + next-layer GEMM -------------------------
// 512 threads: 16 half-waves aggregate 4 passes x 16 nodes writing f16 rows
// straight into the GEMM A-tile in LDS; one __syncthreads; 8-wave MFMA GEMM.
// Bs unions with the aggregation staging (never both live). Weights read
// directly from f32 W ([K][BN]) with transpose-on-stage. edgeSW reads are
// non-temporal (stream-once) to preserve L2 for the h-table's reuse hits.

template<int BN, int H>
__global__ __launch_bounds__(512) void fused_aggemm_kernel(
    const f16* __restrict__ hg,        // gather table [N,128] (prev gemm out)
    const float* __restrict__ als_i,
    const float* __restrict__ ald_i,
    const int* __restrict__ offsets,
    const int2* __restrict__ edgeSW,
    const float* __restrict__ bias,    // aggregate bias [128]
    const float* __restrict__ W,       // next weights f32 [K=128][BN]
    f16* __restrict__ C,               // next h out [N,BN]
    const float* __restrict__ a_src,
    const float* __restrict__ a_dst,
    float* __restrict__ als_o,
    float* __restrict__ ald_o,
    int n_nodes) {
  constexpr int K = 128;
  constexpr int BM = 64;
  constexpr int WN = BN / 4;           // 32 (H=4) or 16 (H=1)
  constexpr int MT = 2, NT = WN / 16;  // NT = 2 or 1
  constexpr int BS_BYTES = BN * 72 * 2;
  constexpr int SW_BYTES = 16 * 32 * 4 + 16 * 4 * 36 * 4;   // swS + swW = 11264
  constexpr int UNI_BYTES = BS_BYTES > SW_BYTES ? BS_BYTES : SW_BYTES;

  __shared__ f16 As[BM * 136];               // 17408 B, live across both phases
  __shared__ __align__(16) char uni[UNI_BYTES];   // Bs  <->  swS+swW
  __shared__ float redS[2][4][32], redD[2][4][32];  // H==1 only (2048 B)

  f16* Bs = (f16*)uni;
  int   (*swS)[32]     = (int(*)[32])uni;
  float (*swW)[4][36]  = (float(*)[4][36])(uni + 16 * 32 * 4);

  int tid = threadIdx.x;
  int hw = tid >> 5, hl = tid & 31;
  int row0 = blockIdx.x * BM;
  int h2 = hl >> 4, l16 = hl & 15;
  int head = l16 >> 2;

  // ---- preload all 4 passes' node info ----
  int startA[4], degA[4];
  float4 aldvA[4];
  #pragma unroll
  for (int p = 0; p < 4; ++p) {
    int node = row0 + p * 16 + hw;
    bool valid = node < n_nodes;
    int nodeC = valid ? node : n_nodes - 1;
    startA[p] = offsets[nodeC];
    int e = offsets[nodeC + 1];
    degA[p] = valid ? e - startA[p] : 0;
    aldvA[p] = *(const float4*)&ald_i[nodeC * 4];
  }
  // prefetch pass 0 edge + als (chained; unavoidable for the first pass)
  int2 eC = make_int2(0, 0);
  if (hl < degA[0]) eC = ntload_int2(&edgeSW[startA[0] + hl]);
  float4 a4C = *(const float4*)&als_i[eC.x * 4];

  // ---- aggregation: 4 passes x 16 nodes -> As ----
  #pragma unroll
  for (int p = 0; p < 4; ++p) {
    int start = startA[p], deg = degA[p];
    bool valid = (row0 + p * 16 + hw) < n_nodes;
    float4 aldv = aldvA[p];

    int s0 = eC.x;
    float wgt0 = __int_as_float(eC.y);
    float v0 = 0.f, v1 = 0.f, v2 = 0.f, v3 = 0.f;
    float m0 = -INFINITY, m1 = -INFINITY, m2 = -INFINITY, m3 = -INFINITY;
    if (hl < deg) {
      v0 = leaky02(a4C.x + aldv.x); m0 = v0;
      v1 = leaky02(a4C.y + aldv.y); m1 = v1;
      v2 = leaky02(a4C.z + aldv.z); m2 = v2;
      v3 = leaky02(a4C.w + aldv.w); m3 = v3;
    } else {
      s0 = 0; wgt0 = 0.f;
    }
    // rare deg > 32 max pass
    for (int j = start + 32 + hl; j < start + deg; j += 32) {
      int2 e = ntload_int2(&edgeSW[j]);
      float4 a4 = *(const float4*)&als_i[e.x * 4];
      m0 = fmaxf(m0, leaky02(a4.x + aldv.x));
      m1 = fmaxf(m1, leaky02(a4.y + aldv.y));
      m2 = fmaxf(m2, leaky02(a4.z + aldv.z));
      m3 = fmaxf(m3, leaky02(a4.w + aldv.w));
    }
    #pragma unroll
    for (int o = 16; o > 0; o >>= 1) {
      m0 = fmaxf(m0, __shfl_xor(m0, o, 32));
      m1 = fmaxf(m1, __shfl_xor(m1, o, 32));
      m2 = fmaxf(m2, __shfl_xor(m2, o, 32));
      m3 = fmaxf(m3, __shfl_xor(m3, o, 32));
    }
    float w0 = 0.f, w1 = 0.f, w2 = 0.f, w3 = 0.f;
    if (hl < deg) {
      w0 = __expf(v0 - m0) * wgt0;
      w1 = __expf(v1 - m1) * wgt0;
      w2 = __expf(v2 - m2) * wgt0;
      w3 = __expf(v3 - m3) * wgt0;
    }
    swS[hw][hl] = s0;
    swW[hw][0][hl] = w0;
    swW[hw][1][hl] = w1;
    swW[hw][2][hl] = w2;
    swW[hw][3][hl] = w3;
    wave_lds_fence();        // wave-private staging: no __syncthreads needed

    float acc0 = 0.f, acc1 = 0.f, acc2 = 0.f, acc3 = 0.f;
    float acc4 = 0.f, acc5 = 0.f, acc6 = 0.f, acc7 = 0.f;
    float dd = 0.f;
    int cn = deg < 32 ? deg : 32;
    int nb = (cn + 15) >> 4;
    for (int b = 0; b < nb; ++b) {
      int j0 = b * 16 + h2 * 8;        // this half owns 8 of the 16 batch edges
      int4   sa = *(const int4*)&swS[hw][j0];
      int4   sb = *(const int4*)&swS[hw][j0 + 4];
      float4 wa = *(const float4*)&swW[hw][head][j0];
      float4 wb = *(const float4*)&swW[hw][head][j0 + 4];
      int   sj[8] = {sa.x, sa.y, sa.z, sa.w, sb.x, sb.y, sb.z, sb.w};
      float wj[8] = {wa.x, wa.y, wa.z, wa.w, wb.x, wb.y, wb.z, wb.w};
      f16x8 hv[8];
      #pragma unroll
      for (int u = 0; u < 8; ++u)
        hv[u] = *(const f16x8*)&hg[(size_t)sj[u] * 128 + 8 * l16];
      #pragma unroll
      for (int u = 0; u < 8; ++u) {
        dd += wj[u];
        acc0 += wj[u] * (float)hv[u][0];
        acc1 += wj[u] * (float)hv[u][1];
        acc2 += wj[u] * (float)hv[u][2];
        acc3 += wj[u] * (float)hv[u][3];
        acc4 += wj[u] * (float)hv[u][4];
        acc5 += wj[u] * (float)hv[u][5];
        acc6 += wj[u] * (float)hv[u][6];
        acc7 += wj[u] * (float)hv[u][7];
      }
    }
    // prefetch next pass's edge record (issued while this pass's work drains)
    int2 eN = make_int2(0, 0);
    if (p < 3 && hl < degA[p + 1]) eN = ntload_int2(&edgeSW[startA[p + 1] + hl]);

    for (int base = start + 32; base < start + deg; base += 32) {  // rare deg > 32
      int cnt = start + deg - base; if (cnt > 32) cnt = 32;
      int st = 0; float u0 = 0.f, u1 = 0.f, u2 = 0.f, u3 = 0.f;
      if (hl < cnt) {
        int2 e = ntload_int2(&edgeSW[base + hl]);
        st = e.x;
        float wg = __int_as_float(e.y);
        float4 a4 = *(const float4*)&als_i[st * 4];
        u0 = __expf(leaky02(a4.x + aldv.x) - m0) * wg;
        u1 = __expf(leaky02(a4.y + aldv.y) - m1) * wg;
        u2 = __expf(leaky02(a4.z + aldv.z) - m2) * wg;
        u3 = __expf(leaky02(a4.w + aldv.w) - m3) * wg;
      }
      for (int jj = h2; jj < cnt; jj += 2) {    // halves split the edge list
        int sjr = __shfl(st, jj, 32);
        float t0 = __shfl(u0, jj, 32), t1 = __shfl(u1, jj, 32);
        float t2 = __shfl(u2, jj, 32), t3 = __shfl(u3, jj, 32);
        float wr = head == 0 ? t0 : head == 1 ? t1 : head == 2 ? t2 : t3;
        f16x8 hv = *(const f16x8*)&hg[(size_t)sjr * 128 + 8 * l16];
        dd += wr;
        acc0 += wr * (float)hv[0];
        acc1 += wr * (float)hv[1];
        acc2 += wr * (float)hv[2];
        acc3 += wr * (float)hv[3];
        acc4 += wr * (float)hv[4];
        acc5 += wr * (float)hv[5];
        acc6 += wr * (float)hv[6];
        acc7 += wr * (float)hv[7];
      }
    }

    // prefetch next pass's als row (depends on eN; overlaps reduce + As write)
    float4 a4N = *(const float4*)&als_i[eN.x * 4];

    acc0 += __shfl_xor(acc0, 16, 32);
    acc1 += __shfl_xor(acc1, 16, 32);
    acc2 += __shfl_xor(acc2, 16, 32);
    acc3 += __shfl_xor(acc3, 16, 32);
    acc4 += __shfl_xor(acc4, 16, 32);
    acc5 += __shfl_xor(acc5, 16, 32);
    acc6 += __shfl_xor(acc6, 16, 32);
    acc7 += __shfl_xor(acc7, 16, 32);
    dd   += __shfl_xor(dd, 16, 32);

    if (h2 == 0) {
      f16x8 val = {0, 0, 0, 0, 0, 0, 0, 0};
      if (valid) {
        float inv = 1.f / (dd + 1e-16f);
        float4 bv0 = *(const float4*)&bias[8 * l16];
        float4 bv1 = *(const float4*)&bias[8 * l16 + 4];
        float o0 = fmaxf(acc0 * inv + bv0.x, 0.f), o1 = fmaxf(acc1 * inv + bv0.y, 0.f);
        float o2 = fmaxf(acc2 * inv + bv0.z, 0.f), o3 = fmaxf(acc3 * inv + bv0.w, 0.f);
        float o4 = fmaxf(acc4 * inv + bv1.x, 0.f), o5 = fmaxf(acc5 * inv + bv1.y, 0.f);
        float o6 = fmaxf(acc6 * inv + bv1.z, 0.f), o7 = fmaxf(acc7 * inv + bv1.w, 0.f);
        val = (f16x8){(f16)o0, (f16)o1, (f16)o2, (f16)o3, (f16)o4, (f16)o5, (f16)o6, (f16)o7};
      }
      *(f16x8*)&As[(p * 16 + hw) * 136 + 8 * l16] = val;
    }
    eC = eN;
    a4C = a4N;
  }

  // ---- GEMM: [64,128] (LDS) @ [128,BN] ----
  int lane = tid & 63, wave = tid >> 6;   // 0..7
  int wm = wave & 1, wn = wave >> 1;      // wn 0..3
  int quad = lane >> 4, cc = lane & 15;

  f32x4 acc[MT][NT];
  #pragma unroll
  for (int mt = 0; mt < MT; ++mt)
    #pragma unroll
    for (int nt = 0; nt < NT; ++nt)
      acc[mt][nt] = (f32x4){0.f, 0.f, 0.f, 0.f};

  for (int k0 = 0; k0 < K; k0 += 64) {
    __syncthreads();   // (first iter: all agg done -> safe to overwrite swS/swW with Bs)
    #pragma unroll
    for (int i = 0; i < (BN * 8) / 512; ++i) {
      int idx = i * 512 + tid;
      int d = idx >> 3, kc = (idx & 7) * 8;
      f16x8 wv;
      #pragma unroll
      for (int j = 0; j < 8; ++j) wv[j] = (f16)W[(size_t)(k0 + kc + j) * BN + d];
      *(f16x8*)&Bs[d * 72 + kc] = wv;
    }
    __syncthreads();
    #pragma unroll
    for (int ki = 0; ki < 2; ++ki) {
      f16x8 a[MT], b[NT];
      #pragma unroll
      for (int mt = 0; mt < MT; ++mt)
        a[mt] = *(const f16x8*)&As[(wm * 32 + mt * 16 + cc) * 136 + k0 + ki * 32 + quad * 8];
      #pragma unroll
      for (int nt = 0; nt < NT; ++nt)
        b[nt] = *(const f16x8*)&Bs[(wn * WN + nt * 16 + cc) * 72 + ki * 32 + quad * 8];
      #pragma unroll
      for (int mt = 0; mt < MT; ++mt)
        #pragma unroll
        for (int nt = 0; nt < NT; ++nt)
          acc[mt][nt] = __builtin_amdgcn_mfma_f32_16x16x32_f16(a[mt], b[nt], acc[mt][nt], 0, 0, 0);
    }
  }

  float asv[NT], adv[NT];
  #pragma unroll
  for (int nt = 0; nt < NT; ++nt) {
    int ch = wn * WN + nt * 16 + cc;
    asv[nt] = a_src[ch];
    adv[nt] = a_dst[ch];
  }

  #pragma unroll
  for (int mt = 0; mt < MT; ++mt)
    #pragma unroll
    for (int v = 0; v < 4; ++v) {
      int row = row0 + wm * 32 + mt * 16 + quad * 4 + v;
      if (row < n_nodes) {
        #pragma unroll
        for (int nt = 0; nt < NT; ++nt)
          C[(size_t)row * BN + wn * WN + nt * 16 + cc] = (f16)acc[mt][nt][v];
      }
      if constexpr (H == 4) {
        // wave wn owns exactly head wn (cols wn*32 .. wn*32+31)
        float s0 = acc[mt][0][v] * asv[0] + acc[mt][1][v] * asv[1];
        float d0 = acc[mt][0][v] * adv[0] + acc[mt][1][v] * adv[1];
        #pragma unroll
        for (int o = 1; o < 16; o <<= 1) {
          s0 += __shfl_xor(s0, o);
          d0 += __shfl_xor(d0, o);
        }
        if (cc == 0 && row < n_nodes) {
          als_o[row * 4 + wn] = s0;
          ald_o[row * 4 + wn] = d0;
        }
      } else {
        float s0 = acc[mt][0][v] * asv[0];
        float d0 = acc[mt][0][v] * adv[0];
        #pragma unroll
        for (int o = 1; o < 16; o <<= 1) {
          s0 += __shfl_xor(s0, o);
          d0 += __shfl_xor(d0, o);
        }
        int r = mt * 16 + quad * 4 + v;
        if (cc == 0) { redS[wm][wn][r] = s0; redD[wm][wn][r] = d0; }
      }
    }
  if constexpr (H == 1) {
    __syncthreads();
    #pragma unroll
    for (int mt = 0; mt < MT; ++mt)
      #pragma unroll
      for (int v = 0; v < 4; ++v) {
        int row = row0 + wm * 32 + mt * 16 + quad * 4 + v;
        int r = mt * 16 + quad * 4 + v;
        if (wn == 0 && cc == 0 && row < n_nodes) {
          als_o[row] = redS[wm][0][r] + redS[wm][1][r] + redS[wm][2][r] + redS[wm][3][r];
          ald_o[row] = redD[wm][0][r] + redD[wm][1][r] + redD[wm][2][r] + redD[wm][3][r];
        }
      }
  }
}

// H == 1, C == 64 (layer 3), fp32 output
__global__ __launch_bounds__(256) void aggregate1_kernel(const f16* __restrict__ h16,
                                                         const float* __restrict__ als,
                                                         const float* __restrict__ ald,
                                                         const int* __restrict__ offsets,
                                                         const int2* __restrict__ edgeSW,
                                                         const float* __restrict__ bias,
                                                         float* __restrict__ out, int n_nodes) {
  __shared__ int   s1s[8][32];
  __shared__ float w1s[8][32];
  int hw = threadIdx.x >> 5;
  int hl = threadIdx.x & 31;
  int node = blockIdx.x * 8 + hw;
  bool valid = node < n_nodes;
  int nodeC = valid ? node : n_nodes - 1;
  int start = offsets[nodeC], end = offsets[nodeC + 1];
  int deg = valid ? end - start : 0;

  float ald0 = ald[nodeC];
  int s0 = 0; float wgt0 = 0.f, v0 = 0.f, m0 = -INFINITY;
  if (hl < deg) {
    int2 e = ntload_int2(&edgeSW[start + hl]);
    s0 = e.x;
    wgt0 = __int_as_float(e.y);
    v0 = leaky02(als[s0] + ald0);
    m0 = v0;
  }
  for (int j = start + 32 + hl; j < end; j += 32) {
    int2 e = ntload_int2(&edgeSW[j]);
    m0 = fmaxf(m0, leaky02(als[e.x] + ald0));
  }
  #pragma unroll
  for (int o = 16; o > 0; o >>= 1) m0 = fmaxf(m0, __shfl_xor(m0, o, 32));

  float w0 = (hl < deg) ? __expf(v0 - m0) * wgt0 : 0.f;
  s1s[hw][hl] = s0;
  w1s[hw][hl] = w0;
  wave_lds_fence();          // wave-private staging: no __syncthreads needed

  int h2 = hl >> 4, l16 = hl & 15;
  float aX = 0.f, aY = 0.f, aZ = 0.f, aW = 0.f, dd = 0.f;
  int cn = deg < 32 ? deg : 32;
  int nb = (cn + 15) >> 4;
  for (int b = 0; b < nb; ++b) {
    int j0 = b * 16 + h2 * 8;
    int4   sa = *(const int4*)&s1s[hw][j0];
    int4   sb = *(const int4*)&s1s[hw][j0 + 4];
    float4 wa = *(const float4*)&w1s[hw][j0];
    float4 wb = *(const float4*)&w1s[hw][j0 + 4];
    int   sj[8] = {sa.x, sa.y, sa.z, sa.w, sb.x, sb.y, sb.z, sb.w};
    float wj[8] = {wa.x, wa.y, wa.z, wa.w, wb.x, wb.y, wb.z, wb.w};
    f16x4 hv[8];
    #pragma unroll
    for (int u = 0; u < 8; ++u)
      hv[u] = *(const f16x4*)&h16[(size_t)sj[u] * 64 + 4 * l16];
    #pragma unroll
    for (int u = 0; u < 8; ++u) {
      dd += wj[u];
      aX += wj[u] * (float)hv[u][0];
      aY += wj[u] * (float)hv[u][1];
      aZ += wj[u] * (float)hv[u][2];
      aW += wj[u] * (float)hv[u][3];
    }
  }
  for (int base = start + 32; base < end; base += 32) {
    int cnt = end - base; if (cnt > 32) cnt = 32;
    int st = 0; float u0 = 0.f;
    if (hl < cnt) {
      int2 e = ntload_int2(&edgeSW[base + hl]);
      st = e.x;
      u0 = __expf(leaky02(als[st] + ald0) - m0) * __int_as_float(e.y);
    }
    for (int jj = h2; jj < cnt; jj += 2) {
      int sjr = __shfl(st, jj, 32);
      float wr = __shfl(u0, jj, 32);
      f16x4 hv = *(const f16x4*)&h16[(size_t)sjr * 64 + 4 * l16];
      dd += wr;
      aX += wr * (float)hv[0];
      aY += wr * (float)hv[1];
      aZ += wr * (float)hv[2];
      aW += wr * (float)hv[3];
    }
  }

  aX += __shfl_xor(aX, 16, 32);
  aY += __shfl_xor(aY, 16, 32);
  aZ += __shfl_xor(aZ, 16, 32);
  aW += __shfl_xor(aW, 16, 32);
  dd += __shfl_xor(dd, 16, 32);

  if (valid && h2 == 0) {
    float inv = 1.f / (dd + 1e-16f);
    float4 bv = *(const float4*)&bias[4 * l16];
    float4 ov = make_float4(aX * inv + bv.x, aY * inv + bv.y,
                            aZ * inv + bv.z, aW * inv + bv.w);
    *(float4*)&out[(size_t)node * 64 + 4 * l16] = ov;
  }
}

// ---------------- launch ----------------

extern "C" void kernel_launch(void* const* d_in, const int* in_sizes, int n_in,
                              void* d_out, int out_size, void* d_ws, size_t ws_size,
                              hipStream_t stream) {
  const int N = NNODES, E = NEDGES;
  const float* x   = (const float*)d_in[0];
  const int*   ei  = (const int*)d_in[1];
  const float* ew  = (const float*)d_in[2];
  const float* W1  = (const float*)d_in[3];
  const float* as1 = (const float*)d_in[4];
  const float* ad1 = (const float*)d_in[5];
  const float* b1  = (const float*)d_in[6];
  const float* W2  = (const float*)d_in[7];
  const float* as2 = (const float*)d_in[8];
  const float* ad2 = (const float*)d_in[9];
  const float* b2  = (const float*)d_in[10];
  const float* W3  = (const float*)d_in[11];
  const float* as3 = (const float*)d_in[12];
  const float* ad3 = (const float*)d_in[13];
  const float* b3  = (const float*)d_in[14];
  const int* src = ei;
  const int* dst = ei + E;

  uint8_t* p = (uint8_t*)d_ws;
  auto carve = [&](size_t bytes) {
    void* r = (void*)p;
    p += (bytes + 255) & ~(size_t)255;
    return r;
  };
  int*   binCursor = (int*)carve((size_t)NBINS * 4);
  int*   offsets   = (int*)carve((size_t)(N + 1) * 4);
  int2*  binned    = (int2*)carve((size_t)NBINS * CAP * 8);
  int2*  edgeSW    = (int2*)carve((size_t)E * 8);
  float* als1      = (float*)carve((size_t)N * 4 * 4);
  float* ald1      = (float*)carve((size_t)N * 4 * 4);
  float* als2      = (float*)carve((size_t)N * 4 * 4);
  float* ald2      = (float*)carve((size_t)N * 4 * 4);
  float* als3      = (float*)carve((size_t)N * 4);
  float* ald3      = (float*)carve((size_t)N * 4);
  f16*   hA16      = (f16*)carve((size_t)N * 128 * 2);   // gemm1 out (layer-1 h)
  f16*   hB16      = (f16*)carve((size_t)N * 128 * 2);   // gemm2 out (layer-2 h)
  f16*   hC16      = (f16*)carve((size_t)N * 64 * 2);    // gemm3 out (layer-3 h)

  int gemmGrid = (N + 63) / 64;     // 782
  int aggGrid = (N + 7) / 8;

  hipMemsetAsync(binCursor, 0, (size_t)NBINS * 4, stream);

  // bin (196 blocks) || layer-1 GEMM (782 blocks)
  fused_front_kernel<<<NBINBLK + gemmGrid, 256, 0, stream>>>(
      dst, src, ew, binCursor, binned, E,
      x, W1, hA16, as1, ad1, als1, ald1, N, 256);
  build_kernel<<<NBINS, 256, 0, stream>>>(binned, binCursor, offsets, edgeSW, N);

  // aggregate layer-1 (gather hA16) + GEMM layer-2 fused; writes hB16, als2/ald2
  fused_aggemm_kernel<128, 4><<<gemmGrid, 512, 0, stream>>>(
      hA16, als1, ald1, offsets, edgeSW, b1,
      W2, hB16, as2, ad2, als2, ald2, N);
  // aggregate layer-2 (gather hB16) + GEMM layer-3 fused; writes hC16, als3/ald3
  fused_aggemm_kernel<64, 1><<<gemmGrid, 512, 0, stream>>>(
      hB16, als2, ald2, offsets, edgeSW, b2,
      W3, hC16, as3, ad3, als3, ald3, N);
  // final aggregate (gather hC16) -> fp32 output
  aggregate1_kernel<<<aggGrid, 256, 0, stream>>>(hC16, als3, ald3, offsets, edgeSW,
                                                 b3, (float*)d_out, N);
}

// Round 8
// 266.769 us; speedup vs baseline: 1.1966x; 1.1966x over previous
//
#include <hip/hip_runtime.h>
#include <math.h>

#define NNODES 50000
#define NEDGES 800000

// binned CSR build
#define BIN_SHIFT 9
#define BIN_W 512
#define NBINS 98            // ceil(50000/512)
#define CAP 12288           // per-bin record capacity (mean 8192 + 45 sigma)
#define ATILE 4096          // edges per bin block
#define NBINBLK ((NEDGES + ATILE - 1) / ATILE)   // 196

typedef _Float16 f16;
typedef __attribute__((ext_vector_type(2))) _Float16 f16x2;
typedef __attribute__((ext_vector_type(4))) _Float16 f16x4;
typedef __attribute__((ext_vector_type(8))) _Float16 f16x8;
typedef __attribute__((ext_vector_type(4))) float f32x4;

__device__ __forceinline__ float leaky02(float v) { return v > 0.f ? v : 0.2f * v; }

// wave-local LDS visibility (staging is private per half-wave; wave lockstep)
__device__ __forceinline__ void wave_lds_fence() {
  __asm__ volatile("s_waitcnt lgkmcnt(0)" ::: "memory");
}

// ---------------- init: zero bin cursors + fp16 weight transposes ----------------

__global__ __launch_bounds__(256) void init_kernel(int* __restrict__ binCursor,
                                                   const float* __restrict__ W1,
                                                   const float* __restrict__ W2,
                                                   const float* __restrict__ W3,
                                                   f16* __restrict__ WT1,
                                                   f16* __restrict__ WT2,
                                                   f16* __restrict__ WT3) {
  int gid = blockIdx.x * 256 + threadIdx.x;
  int stride = gridDim.x * 256;
  if (gid < NBINS) binCursor[gid] = 0;
  for (int i = gid; i < 32768; i += stride) {       // W1: K=256, D=128
    int d = i >> 8, k = i & 255;
    WT1[i] = (f16)W1[k * 128 + d];
  }
  for (int i = gid; i < 16384; i += stride) {       // W2: K=128, D=128
    int d = i >> 7, k = i & 127;
    WT2[i] = (f16)W2[k * 128 + d];
  }
  for (int i = gid; i < 8192; i += stride) {        // W3: K=128, D=64
    int d = i >> 7, k = i & 127;
    WT3[i] = (f16)W3[k * 64 + d];
  }
}

// ---------------- phase A: bin edges by dst-range (device body) ----------------

__device__ __forceinline__ void bin_body(int bid,
                                         const int* __restrict__ dst,
                                         const int* __restrict__ src,
                                         const float* __restrict__ ew,
                                         int* __restrict__ binCursor,
                                         int2* __restrict__ binned, int ne) {
  __shared__ int cnt[NBINS];
  __shared__ int gbase[NBINS];
  int tid = threadIdx.x;
  int t0 = bid * ATILE;
  if (tid < NBINS) cnt[tid] = 0;
  __syncthreads();
  int saved[ATILE / 256];
  #pragma unroll
  for (int u = 0; u < ATILE / 256; ++u) {
    int i = t0 + u * 256 + tid;
    int v = 0;
    if (i < ne) {
      int d = dst[i];                               // d < 65536 -> 16 bits
      int idx = atomicAdd(&cnt[d >> BIN_SHIFT], 1); // idx < 4096 -> 12 bits
      v = d | (idx << 16);
    }
    saved[u] = v;
  }
  __syncthreads();
  if (tid < NBINS) gbase[tid] = atomicAdd(&binCursor[tid], cnt[tid]);
  __syncthreads();
  #pragma unroll
  for (int u = 0; u < ATILE / 256; ++u) {
    int i = t0 + u * 256 + tid;
    if (i < ne) {
      int v = saved[u];
      int d = v & 0xffff;
      int idx = (int)((unsigned)v >> 16);
      int b = d >> BIN_SHIFT;
      int slot = gbase[b] + idx;
      if (slot < CAP)                               // statistically never taken
        binned[(size_t)b * CAP + slot] =
            make_int2(src[i] | (d << 16), __float_as_int(ew[i]));
    }
  }
}

// ---------------- phase B: per-bin CSR finalize ----------------

__global__ __launch_bounds__(256) void build_kernel(const int2* __restrict__ binned,
                                                    const int* __restrict__ binCursor,
                                                    int* __restrict__ offsets,
                                                    int2* __restrict__ edgeSW, int n) {
  __shared__ int sizes[NBINS];
  __shared__ int cnt[BIN_W];
  __shared__ int wsum[4];
  __shared__ int bstartS;
  int tid = threadIdx.x;
  int b = blockIdx.x;
  if (tid < NBINS) sizes[tid] = binCursor[tid];
  cnt[tid] = 0;
  cnt[tid + 256] = 0;
  __syncthreads();
  if (tid == 0) {
    int s = 0;
    for (int k = 0; k < b; ++k) s += (sizes[k] < CAP ? sizes[k] : CAP);
    bstartS = s;
  }
  int mySize = sizes[b];
  if (mySize > CAP) mySize = CAP;
  __syncthreads();
  const int2* mybin = binned + (size_t)b * CAP;
  for (int i = tid; i < mySize; i += 256)
    atomicAdd(&cnt[((unsigned)mybin[i].x >> 16) - b * BIN_W], 1);
  __syncthreads();
  int c0 = cnt[2 * tid], c1 = cnt[2 * tid + 1];
  int s2 = c0 + c1;
  int lane = tid & 63, wid = tid >> 6;
  int incl = s2;
  #pragma unroll
  for (int o = 1; o < 64; o <<= 1) {
    int u = __shfl_up(incl, o, 64);
    if (lane >= o) incl += u;
  }
  if (lane == 63) wsum[wid] = incl;
  __syncthreads();
  if (tid == 0) {
    int r = 0;
    #pragma unroll
    for (int w = 0; w < 4; ++w) { int t = wsum[w]; wsum[w] = r; r += t; }
  }
  __syncthreads();
  int excl0 = bstartS + wsum[wid] + incl - s2;  // global CSR start of node 2*tid
  int excl1 = excl0 + c0;
  int node0 = b * BIN_W;
  if (node0 + 2 * tid < n)     offsets[node0 + 2 * tid]     = excl0;
  if (node0 + 2 * tid + 1 < n) offsets[node0 + 2 * tid + 1] = excl1;
  if (b == NBINS - 1 && tid == 0) offsets[n] = bstartS + mySize;
  __syncthreads();
  cnt[2 * tid] = excl0;                         // becomes the global-position cursor
  cnt[2 * tid + 1] = excl1;
  __syncthreads();
  for (int i = tid; i < mySize; i += 256) {
    int2 r = mybin[i];
    int dloc = (int)((unsigned)r.x >> 16) - b * BIN_W;
    int pos = atomicAdd(&cnt[dloc], 1);
    edgeSW[pos] = make_int2(r.x & 0xffff, r.y);
  }
}

// ---------------- fp16 MFMA GEMM + fused attention-logit epilogue -----------
// 256-thread 4-wave version (layer 1 inside the fused front); fp16 WT input.

template<int BN>
__device__ __forceinline__ void gemm_body(int bid,
                                          const float* __restrict__ A,
                                          const f16* __restrict__ BT,
                                          f16* __restrict__ C,
                                          const float* __restrict__ a_src,
                                          const float* __restrict__ a_dst,
                                          float* __restrict__ als,
                                          float* __restrict__ ald,
                                          int M, int K) {
  constexpr int BM = 64;
  constexpr int WN = BN / 2;
  constexpr int MT = 2, NT = WN / 16;
  __shared__ f16 As[BM * 72];
  __shared__ f16 Bs[BN * 72];
  int tid = threadIdx.x;
  int lane = tid & 63, wave = tid >> 6;
  int wm = wave & 1, wn = wave >> 1;
  int row0 = bid * BM;
  int quad = lane >> 4, cc = lane & 15;

  f32x4 acc[MT][NT];
  #pragma unroll
  for (int mt = 0; mt < MT; ++mt)
    #pragma unroll
    for (int nt = 0; nt < NT; ++nt)
      acc[mt][nt] = (f32x4){0.f, 0.f, 0.f, 0.f};

  for (int k0 = 0; k0 < K; k0 += 64) {
    __syncthreads();
    #pragma unroll
    for (int i = 0; i < 4; ++i) {
      int r = i * 16 + (tid >> 4);
      int kc = (tid & 15) * 4;
      float4 av = make_float4(0.f, 0.f, 0.f, 0.f);
      if (row0 + r < M) av = *(const float4*)&A[(size_t)(row0 + r) * K + k0 + kc];
      *(f16x4*)&As[r * 72 + kc] = (f16x4){(f16)av.x, (f16)av.y, (f16)av.z, (f16)av.w};
    }
    #pragma unroll
    for (int i = 0; i < BN / 32; ++i) {
      int d = i * 32 + (tid >> 3);
      int kc = (tid & 7) * 8;
      *(f16x8*)&Bs[d * 72 + kc] = *(const f16x8*)&BT[(size_t)d * K + k0 + kc];
    }
    __syncthreads();
    #pragma unroll
    for (int ki = 0; ki < 2; ++ki) {
      f16x8 a[MT], b[NT];
      #pragma unroll
      for (int mt = 0; mt < MT; ++mt)
        a[mt] = *(const f16x8*)&As[(wm * 32 + mt * 16 + cc) * 72 + ki * 32 + quad * 8];
      #pragma unroll
      for (int nt = 0; nt < NT; ++nt)
        b[nt] = *(const f16x8*)&Bs[(wn * WN + nt * 16 + cc) * 72 + ki * 32 + quad * 8];
      #pragma unroll
      for (int mt = 0; mt < MT; ++mt)
        #pragma unroll
        for (int nt = 0; nt < NT; ++nt)
          acc[mt][nt] = __builtin_amdgcn_mfma_f32_16x16x32_f16(a[mt], b[nt], acc[mt][nt], 0, 0, 0);
    }
  }

  float asv[NT], adv[NT];
  #pragma unroll
  for (int nt = 0; nt < NT; ++nt) {
    int ch = wn * WN + nt * 16 + cc;
    asv[nt] = a_src[ch];
    adv[nt] = a_dst[ch];
  }

  #pragma unroll
  for (int mt = 0; mt < MT; ++mt)
    #pragma unroll
    for (int v = 0; v < 4; ++v) {
      int row = row0 + wm * 32 + mt * 16 + quad * 4 + v;
      if (row < M) {
        #pragma unroll
        for (int nt = 0; nt < NT; ++nt)
          C[(size_t)row * BN + wn * WN + nt * 16 + cc] = (f16)acc[mt][nt][v];
      }
      float s0 = acc[mt][0][v] * asv[0] + acc[mt][1][v] * asv[1];
      float s1 = acc[mt][2][v] * asv[2] + acc[mt][3][v] * asv[3];
      float d0 = acc[mt][0][v] * adv[0] + acc[mt][1][v] * adv[1];
      float d1 = acc[mt][2][v] * adv[2] + acc[mt][3][v] * adv[3];
      #pragma unroll
      for (int o = 1; o < 16; o <<= 1) {
        s0 += __shfl_xor(s0, o);
        s1 += __shfl_xor(s1, o);
        d0 += __shfl_xor(d0, o);
        d1 += __shfl_xor(d1, o);
      }
      if (cc == 0 && row < M) {
        *(float2*)&als[row * 4 + 2 * wn] = make_float2(s0, s1);
        *(float2*)&ald[row * 4 + 2 * wn] = make_float2(d0, d1);
      }
    }
}

// ---------------- fused front: bin (196 blocks) || gemm1 (782 blocks) -------

__global__ __launch_bounds__(256) void fused_front_kernel(const int* __restrict__ dst,
                                                          const int* __restrict__ src,
                                                          const float* __restrict__ ew,
                                                          int* __restrict__ binCursor,
                                                          int2* __restrict__ binned, int ne,
                                                          const float* __restrict__ A,
                                                          const f16* __restrict__ BT,
                                                          f16* __restrict__ C,
                                                          const float* __restrict__ a_src,
                                                          const float* __restrict__ a_dst,
                                                          float* __restrict__ als,
                                                          float* __restrict__ ald,
                                                          int M, int K) {
  if (blockIdx.x < NBINBLK)
    bin_body(blockIdx.x, dst, src, ew, binCursor, binned, ne);
  else
    gemm_body<128>(blockIdx.x - NBINBLK, A, BT, C, a_src, a_dst, als, ald, M, K);
}

// ---------------- fused aggregate + next-layer GEMM -------------------------
// R8: BM=32 (was 64) -> grid 1563 blocks. Gather phase is concurrency-limited
// (standalone 2.5 TB/s @33% occ vs fused 2.1 @28%); LDS 28.2 KB -> 5 blocks/CU
// x 8 waves = 40 >= 32-wave cap, so aggregation can now fill the CU. 512 thr:
// 16 half-waves x 2 passes x 16 nodes -> As; 8-wave MFMA GEMM (2m x 4n) on
// the 32x128 tile. Bs unions with aggregation staging (never both live).

template<int BN, int H>
__global__ __launch_bounds__(512) void fused_aggemm_kernel(
    const f16* __restrict__ hg,        // gather table [N,128] (prev gemm out)
    const float* __restrict__ als_i,
    const float* __restrict__ ald_i,
    const int* __restrict__ offsets,
    const int2* __restrict__ edgeSW,
    const float* __restrict__ bias,    // aggregate bias [128]
    const f16* __restrict__ BT,        // next weights fp16 [BN][K=128]
    f16* __restrict__ C,               // next h out [N,BN]
    const float* __restrict__ a_src,
    const float* __restrict__ a_dst,
    float* __restrict__ als_o,
    float* __restrict__ ald_o,
    int n_nodes) {
  constexpr int K = 128;
  constexpr int BM = 32;
  constexpr int WN = BN / 4;           // 32 (H=4) or 16 (H=1)
  constexpr int NT = WN / 16;          // 2 or 1
  constexpr int BS_BYTES = BN * 72 * 2;
  constexpr int SW_BYTES = 16 * 32 * 4 + 16 * 4 * 36 * 4;   // swS + swW = 11264
  constexpr int UNI_BYTES = BS_BYTES > SW_BYTES ? BS_BYTES : SW_BYTES;

  __shared__ f16 As[BM * 136];               // 8704 B, live across both phases
  __shared__ __align__(16) char uni[UNI_BYTES];   // Bs  <->  swS+swW
  __shared__ float redS[2][4][16], redD[2][4][16];  // H==1 only (1024 B)

  f16* Bs = (f16*)uni;
  int   (*swS)[32]     = (int(*)[32])uni;
  float (*swW)[4][36]  = (float(*)[4][36])(uni + 16 * 32 * 4);

  int tid = threadIdx.x;
  int hw = tid >> 5, hl = tid & 31;
  int row0 = blockIdx.x * BM;
  int h2 = hl >> 4, l16 = hl & 15;
  int head = l16 >> 2;

  // ---- preload both passes' node info ----
  int startA[2], degA[2];
  float4 aldvA[2];
  #pragma unroll
  for (int p = 0; p < 2; ++p) {
    int node = row0 + p * 16 + hw;
    bool valid = node < n_nodes;
    int nodeC = valid ? node : n_nodes - 1;
    startA[p] = offsets[nodeC];
    int e = offsets[nodeC + 1];
    degA[p] = valid ? e - startA[p] : 0;
    aldvA[p] = *(const float4*)&ald_i[nodeC * 4];
  }
  // prefetch pass 0 edge + als (chained; unavoidable for the first pass)
  int2 eC = make_int2(0, 0);
  if (hl < degA[0]) eC = edgeSW[startA[0] + hl];
  float4 a4C = *(const float4*)&als_i[eC.x * 4];

  // ---- aggregation: 2 passes x 16 nodes -> As ----
  #pragma unroll
  for (int p = 0; p < 2; ++p) {
    int start = startA[p], deg = degA[p];
    bool valid = (row0 + p * 16 + hw) < n_nodes;
    float4 aldv = aldvA[p];

    int s0 = eC.x;
    float wgt0 = __int_as_float(eC.y);
    float v0 = 0.f, v1 = 0.f, v2 = 0.f, v3 = 0.f;
    float m0 = -INFINITY, m1 = -INFINITY, m2 = -INFINITY, m3 = -INFINITY;
    if (hl < deg) {
      v0 = leaky02(a4C.x + aldv.x); m0 = v0;
      v1 = leaky02(a4C.y + aldv.y); m1 = v1;
      v2 = leaky02(a4C.z + aldv.z); m2 = v2;
      v3 = leaky02(a4C.w + aldv.w); m3 = v3;
    } else {
      s0 = 0; wgt0 = 0.f;
    }
    // rare deg > 32 max pass
    for (int j = start + 32 + hl; j < start + deg; j += 32) {
      int2 e = edgeSW[j];
      float4 a4 = *(const float4*)&als_i[e.x * 4];
      m0 = fmaxf(m0, leaky02(a4.x + aldv.x));
      m1 = fmaxf(m1, leaky02(a4.y + aldv.y));
      m2 = fmaxf(m2, leaky02(a4.z + aldv.z));
      m3 = fmaxf(m3, leaky02(a4.w + aldv.w));
    }
    #pragma unroll
    for (int o = 16; o > 0; o >>= 1) {
      m0 = fmaxf(m0, __shfl_xor(m0, o, 32));
      m1 = fmaxf(m1, __shfl_xor(m1, o, 32));
      m2 = fmaxf(m2, __shfl_xor(m2, o, 32));
      m3 = fmaxf(m3, __shfl_xor(m3, o, 32));
    }
    float w0 = 0.f, w1 = 0.f, w2 = 0.f, w3 = 0.f;
    if (hl < deg) {
      w0 = __expf(v0 - m0) * wgt0;
      w1 = __expf(v1 - m1) * wgt0;
      w2 = __expf(v2 - m2) * wgt0;
      w3 = __expf(v3 - m3) * wgt0;
    }
    swS[hw][hl] = s0;
    swW[hw][0][hl] = w0;
    swW[hw][1][hl] = w1;
    swW[hw][2][hl] = w2;
    swW[hw][3][hl] = w3;
    wave_lds_fence();        // wave-private staging: no __syncthreads needed

    float acc0 = 0.f, acc1 = 0.f, acc2 = 0.f, acc3 = 0.f;
    float acc4 = 0.f, acc5 = 0.f, acc6 = 0.f, acc7 = 0.f;
    float dd = 0.f;
    int cn = deg < 32 ? deg : 32;
    int nb = (cn + 15) >> 4;
    for (int b = 0; b < nb; ++b) {
      int j0 = b * 16 + h2 * 8;        // this half owns 8 of the 16 batch edges
      int4   sa = *(const int4*)&swS[hw][j0];
      int4   sb = *(const int4*)&swS[hw][j0 + 4];
      float4 wa = *(const float4*)&swW[hw][head][j0];
      float4 wb = *(const float4*)&swW[hw][head][j0 + 4];
      int   sj[8] = {sa.x, sa.y, sa.z, sa.w, sb.x, sb.y, sb.z, sb.w};
      float wj[8] = {wa.x, wa.y, wa.z, wa.w, wb.x, wb.y, wb.z, wb.w};
      f16x8 hv[8];
      #pragma unroll
      for (int u = 0; u < 8; ++u)
        hv[u] = *(const f16x8*)&hg[(size_t)sj[u] * 128 + 8 * l16];
      #pragma unroll
      for (int u = 0; u < 8; ++u) {
        dd += wj[u];
        acc0 += wj[u] * (float)hv[u][0];
        acc1 += wj[u] * (float)hv[u][1];
        acc2 += wj[u] * (float)hv[u][2];
        acc3 += wj[u] * (float)hv[u][3];
        acc4 += wj[u] * (float)hv[u][4];
        acc5 += wj[u] * (float)hv[u][5];
        acc6 += wj[u] * (float)hv[u][6];
        acc7 += wj[u] * (float)hv[u][7];
      }
    }
    // prefetch next pass's edge record (issued while this pass's work drains)
    int2 eN = make_int2(0, 0);
    if (p < 1 && hl < degA[p + 1]) eN = edgeSW[startA[p + 1] + hl];

    for (int base = start + 32; base < start + deg; base += 32) {  // rare deg > 32
      int cnt = start + deg - base; if (cnt > 32) cnt = 32;
      int st = 0; float u0 = 0.f, u1 = 0.f, u2 = 0.f, u3 = 0.f;
      if (hl < cnt) {
        int2 e = edgeSW[base + hl];
        st = e.x;
        float wg = __int_as_float(e.y);
        float4 a4 = *(const float4*)&als_i[st * 4];
        u0 = __expf(leaky02(a4.x + aldv.x) - m0) * wg;
        u1 = __expf(leaky02(a4.y + aldv.y) - m1) * wg;
        u2 = __expf(leaky02(a4.z + aldv.z) - m2) * wg;
        u3 = __expf(leaky02(a4.w + aldv.w) - m3) * wg;
      }
      for (int jj = h2; jj < cnt; jj += 2) {    // halves split the edge list
        int sjr = __shfl(st, jj, 32);
        float t0 = __shfl(u0, jj, 32), t1 = __shfl(u1, jj, 32);
        float t2 = __shfl(u2, jj, 32), t3 = __shfl(u3, jj, 32);
        float wr = head == 0 ? t0 : head == 1 ? t1 : head == 2 ? t2 : t3;
        f16x8 hv = *(const f16x8*)&hg[(size_t)sjr * 128 + 8 * l16];
        dd += wr;
        acc0 += wr * (float)hv[0];
        acc1 += wr * (float)hv[1];
        acc2 += wr * (float)hv[2];
        acc3 += wr * (float)hv[3];
        acc4 += wr * (float)hv[4];
        acc5 += wr * (float)hv[5];
        acc6 += wr * (float)hv[6];
        acc7 += wr * (float)hv[7];
      }
    }

    // prefetch next pass's als row (depends on eN; overlaps reduce + As write)
    float4 a4N = *(const float4*)&als_i[eN.x * 4];

    acc0 += __shfl_xor(acc0, 16, 32);
    acc1 += __shfl_xor(acc1, 16, 32);
    acc2 += __shfl_xor(acc2, 16, 32);
    acc3 += __shfl_xor(acc3, 16, 32);
    acc4 += __shfl_xor(acc4, 16, 32);
    acc5 += __shfl_xor(acc5, 16, 32);
    acc6 += __shfl_xor(acc6, 16, 32);
    acc7 += __shfl_xor(acc7, 16, 32);
    dd   += __shfl_xor(dd, 16, 32);

    if (h2 == 0) {
      f16x8 val = {0, 0, 0, 0, 0, 0, 0, 0};
      if (valid) {
        float inv = 1.f / (dd + 1e-16f);
        float4 bv0 = *(const float4*)&bias[8 * l16];
        float4 bv1 = *(const float4*)&bias[8 * l16 + 4];
        float o0 = fmaxf(acc0 * inv + bv0.x, 0.f), o1 = fmaxf(acc1 * inv + bv0.y, 0.f);
        float o2 = fmaxf(acc2 * inv + bv0.z, 0.f), o3 = fmaxf(acc3 * inv + bv0.w, 0.f);
        float o4 = fmaxf(acc4 * inv + bv1.x, 0.f), o5 = fmaxf(acc5 * inv + bv1.y, 0.f);
        float o6 = fmaxf(acc6 * inv + bv1.z, 0.f), o7 = fmaxf(acc7 * inv + bv1.w, 0.f);
        val = (f16x8){(f16)o0, (f16)o1, (f16)o2, (f16)o3, (f16)o4, (f16)o5, (f16)o6, (f16)o7};
      }
      *(f16x8*)&As[(p * 16 + hw) * 136 + 8 * l16] = val;
    }
    eC = eN;
    a4C = a4N;
  }

  // ---- GEMM: [32,128] (LDS) @ [128,BN], 8 waves (2m x 4n) ----
  int lane = tid & 63, wave = tid >> 6;   // 0..7
  int wm = wave & 1, wn = wave >> 1;      // wn 0..3
  int quad = lane >> 4, cc = lane & 15;

  f32x4 acc[NT];
  #pragma unroll
  for (int nt = 0; nt < NT; ++nt)
    acc[nt] = (f32x4){0.f, 0.f, 0.f, 0.f};

  for (int k0 = 0; k0 < K; k0 += 64) {
    __syncthreads();   // (first iter: all agg done -> safe to overwrite swS/swW with Bs)
    #pragma unroll
    for (int i = 0; i < (BN * 8) / 512; ++i) {
      int idx = i * 512 + tid;
      int d = idx >> 3, kc = (idx & 7) * 8;
      *(f16x8*)&Bs[d * 72 + kc] = *(const f16x8*)&BT[(size_t)d * K + k0 + kc];
    }
    __syncthreads();
    #pragma unroll
    for (int ki = 0; ki < 2; ++ki) {
      f16x8 a = *(const f16x8*)&As[(wm * 16 + cc) * 136 + k0 + ki * 32 + quad * 8];
      f16x8 b[NT];
      #pragma unroll
      for (int nt = 0; nt < NT; ++nt)
        b[nt] = *(const f16x8*)&Bs[(wn * WN + nt * 16 + cc) * 72 + ki * 32 + quad * 8];
      #pragma unroll
      for (int nt = 0; nt < NT; ++nt)
        acc[nt] = __builtin_amdgcn_mfma_f32_16x16x32_f16(a, b[nt], acc[nt], 0, 0, 0);
    }
  }

  float asv[NT], adv[NT];
  #pragma unroll
  for (int nt = 0; nt < NT; ++nt) {
    int ch = wn * WN + nt * 16 + cc;
    asv[nt] = a_src[ch];
    adv[nt] = a_dst[ch];
  }

  #pragma unroll
  for (int v = 0; v < 4; ++v) {
    int row = row0 + wm * 16 + quad * 4 + v;
    if (row < n_nodes) {
      #pragma unroll
      for (int nt = 0; nt < NT; ++nt)
        C[(size_t)row * BN + wn * WN + nt * 16 + cc] = (f16)acc[nt][v];
    }
    if constexpr (H == 4) {
      // wave wn owns exactly head wn (cols wn*32 .. wn*32+31)
      float s0 = acc[0][v] * asv[0] + acc[1][v] * asv[1];
      float d0 = acc[0][v] * adv[0] + acc[1][v] * adv[1];
      #pragma unroll
      for (int o = 1; o < 16; o <<= 1) {
        s0 += __shfl_xor(s0, o);
        d0 += __shfl_xor(d0, o);
      }
      if (cc == 0 && row < n_nodes) {
        als_o[row * 4 + wn] = s0;
        ald_o[row * 4 + wn] = d0;
      }
    } else {
      float s0 = acc[0][v] * asv[0];
      float d0 = acc[0][v] * adv[0];
      #pragma unroll
      for (int o = 1; o < 16; o <<= 1) {
        s0 += __shfl_xor(s0, o);
        d0 += __shfl_xor(d0, o);
      }
      int r = quad * 4 + v;
      if (cc == 0) { redS[wm][wn][r] = s0; redD[wm][wn][r] = d0; }
    }
  }
  if constexpr (H == 1) {
    __syncthreads();
    #pragma unroll
    for (int v = 0; v < 4; ++v) {
      int row = row0 + wm * 16 + quad * 4 + v;
      int r = quad * 4 + v;
      if (wn == 0 && cc == 0 && row < n_nodes) {
        als_o[row] = redS[wm][0][r] + redS[wm][1][r] + redS[wm][2][r] + redS[wm][3][r];
        ald_o[row] = redD[wm][0][r] + redD[wm][1][r] + redD[wm][2][r] + redD[wm][3][r];
      }
    }
  }
}

// H == 1, C == 64 (layer 3), fp32 output
__global__ __launch_bounds__(256) void aggregate1_kernel(const f16* __restrict__ h16,
                                                         const float* __restrict__ als,
                                                         const float* __restrict__ ald,
                                                         const int* __restrict__ offsets,
                                                         const int2* __restrict__ edgeSW,
                                                         const float* __restrict__ bias,
                                                         float* __restrict__ out, int n_nodes) {
  __shared__ int   s1s[8][32];
  __shared__ float w1s[8][32];
  int hw = threadIdx.x >> 5;
  int hl = threadIdx.x & 31;
  int node = blockIdx.x * 8 + hw;
  bool valid = node < n_nodes;
  int nodeC = valid ? node : n_nodes - 1;
  int start = offsets[nodeC], end = offsets[nodeC + 1];
  int deg = valid ? end - start : 0;

  float ald0 = ald[nodeC];
  int s0 = 0; float wgt0 = 0.f, v0 = 0.f, m0 = -INFINITY;
  if (hl < deg) {
    int2 e = edgeSW[start + hl];
    s0 = e.x;
    wgt0 = __int_as_float(e.y);
    v0 = leaky02(als[s0] + ald0);
    m0 = v0;
  }
  for (int j = start + 32 + hl; j < end; j += 32) {
    int2 e = edgeSW[j];
    m0 = fmaxf(m0, leaky02(als[e.x] + ald0));
  }
  #pragma unroll
  for (int o = 16; o > 0; o >>= 1) m0 = fmaxf(m0, __shfl_xor(m0, o, 32));

  float w0 = (hl < deg) ? __expf(v0 - m0) * wgt0 : 0.f;
  s1s[hw][hl] = s0;
  w1s[hw][hl] = w0;
  wave_lds_fence();          // wave-private staging: no __syncthreads needed

  int h2 = hl >> 4, l16 = hl & 15;
  float aX = 0.f, aY = 0.f, aZ = 0.f, aW = 0.f, dd = 0.f;
  int cn = deg < 32 ? deg : 32;
  int nb = (cn + 15) >> 4;
  for (int b = 0; b < nb; ++b) {
    int j0 = b * 16 + h2 * 8;
    int4   sa = *(const int4*)&s1s[hw][j0];
    int4   sb = *(const int4*)&s1s[hw][j0 + 4];
    float4 wa = *(const float4*)&w1s[hw][j0];
    float4 wb = *(const float4*)&w1s[hw][j0 + 4];
    int   sj[8] = {sa.x, sa.y, sa.z, sa.w, sb.x, sb.y, sb.z, sb.w};
    float wj[8] = {wa.x, wa.y, wa.z, wa.w, wb.x, wb.y, wb.z, wb.w};
    f16x4 hv[8];
    #pragma unroll
    for (int u = 0; u < 8; ++u)
      hv[u] = *(const f16x4*)&h16[(size_t)sj[u] * 64 + 4 * l16];
    #pragma unroll
    for (int u = 0; u < 8; ++u) {
      dd += wj[u];
      aX += wj[u] * (float)hv[u][0];
      aY += wj[u] * (float)hv[u][1];
      aZ += wj[u] * (float)hv[u][2];
      aW += wj[u] * (float)hv[u][3];
    }
  }
  for (int base = start + 32; base < end; base += 32) {
    int cnt = end - base; if (cnt > 32) cnt = 32;
    int st = 0; float u0 = 0.f;
    if (hl < cnt) {
      int2 e = edgeSW[base + hl];
      st = e.x;
      u0 = __expf(leaky02(als[st] + ald0) - m0) * __int_as_float(e.y);
    }
    for (int jj = h2; jj < cnt; jj += 2) {
      int sjr = __shfl(st, jj, 32);
      float wr = __shfl(u0, jj, 32);
      f16x4 hv = *(const f16x4*)&h16[(size_t)sjr * 64 + 4 * l16];
      dd += wr;
      aX += wr * (float)hv[0];
      aY += wr * (float)hv[1];
      aZ += wr * (float)hv[2];
      aW += wr * (float)hv[3];
    }
  }

  aX += __shfl_xor(aX, 16, 32);
  aY += __shfl_xor(aY, 16, 32);
  aZ += __shfl_xor(aZ, 16, 32);
  aW += __shfl_xor(aW, 16, 32);
  dd += __shfl_xor(dd, 16, 32);

  if (valid && h2 == 0) {
    float inv = 1.f / (dd + 1e-16f);
    float4 bv = *(const float4*)&bias[4 * l16];
    float4 ov = make_float4(aX * inv + bv.x, aY * inv + bv.y,
                            aZ * inv + bv.z, aW * inv + bv.w);
    *(float4*)&out[(size_t)node * 64 + 4 * l16] = ov;
  }
}

// ---------------- launch ----------------

extern "C" void kernel_launch(void* const* d_in, const int* in_sizes, int n_in,
                              void* d_out, int out_size, void* d_ws, size_t ws_size,
                              hipStream_t stream) {
  const int N = NNODES, E = NEDGES;
  const float* x   = (const float*)d_in[0];
  const int*   ei  = (const int*)d_in[1];
  const float* ew  = (const float*)d_in[2];
  const float* W1  = (const float*)d_in[3];
  const float* as1 = (const float*)d_in[4];
  const float* ad1 = (const float*)d_in[5];
  const float* b1  = (const float*)d_in[6];
  const float* W2  = (const float*)d_in[7];
  const float* as2 = (const float*)d_in[8];
  const float* ad2 = (const float*)d_in[9];
  const float* b2  = (const float*)d_in[10];
  const float* W3  = (const float*)d_in[11];
  const float* as3 = (const float*)d_in[12];
  const float* ad3 = (const float*)d_in[13];
  const float* b3  = (const float*)d_in[14];
  const int* src = ei;
  const int* dst = ei + E;

  uint8_t* p = (uint8_t*)d_ws;
  auto carve = [&](size_t bytes) {
    void* r = (void*)p;
    p += (bytes + 255) & ~(size_t)255;
    return r;
  };
  int*   binCursor = (int*)carve((size_t)NBINS * 4);
  int*   offsets   = (int*)carve((size_t)(N + 1) * 4);
  int2*  binned    = (int2*)carve((size_t)NBINS * CAP * 8);
  int2*  edgeSW    = (int2*)carve((size_t)E * 8);
  float* als1      = (float*)carve((size_t)N * 4 * 4);
  float* ald1      = (float*)carve((size_t)N * 4 * 4);
  float* als2      = (float*)carve((size_t)N * 4 * 4);
  float* ald2      = (float*)carve((size_t)N * 4 * 4);
  float* als3      = (float*)carve((size_t)N * 4);
  float* ald3      = (float*)carve((size_t)N * 4);
  f16*   hA16      = (f16*)carve((size_t)N * 128 * 2);   // gemm1 out (layer-1 h)
  f16*   hB16      = (f16*)carve((size_t)N * 128 * 2);   // gemm2 out (layer-2 h)
  f16*   hC16      = (f16*)carve((size_t)N * 64 * 2);    // gemm3 out (layer-3 h)
  f16*   WT1       = (f16*)carve((size_t)256 * 128 * 2);
  f16*   WT2       = (f16*)carve((size_t)128 * 128 * 2);
  f16*   WT3       = (f16*)carve((size_t)128 * 64 * 2);

  int gemmGrid = (N + 63) / 64;      // 782 (front gemm1)
  int aggemmGrid = (N + 31) / 32;    // 1563 (fused agg+gemm)
  int aggGrid = (N + 7) / 8;

  init_kernel<<<128, 256, 0, stream>>>(binCursor, W1, W2, W3, WT1, WT2, WT3);

  // bin (196 blocks) || layer-1 GEMM (782 blocks)
  fused_front_kernel<<<NBINBLK + gemmGrid, 256, 0, stream>>>(
      dst, src, ew, binCursor, binned, E,
      x, WT1, hA16, as1, ad1, als1, ald1, N, 256);
  build_kernel<<<NBINS, 256, 0, stream>>>(binned, binCursor, offsets, edgeSW, N);

  // aggregate layer-1 (gather hA16) + GEMM layer-2 fused; writes hB16, als2/ald2
  fused_aggemm_kernel<128, 4><<<aggemmGrid, 512, 0, stream>>>(
      hA16, als1, ald1, offsets, edgeSW, b1,
      WT2, hB16, as2, ad2, als2, ald2, N);
  // aggregate layer-2 (gather hB16) + GEMM layer-3 fused; writes hC16, als3/ald3
  fused_aggemm_kernel<64, 1><<<aggemmGrid, 512, 0, stream>>>(
      hB16, als2, ald2, offsets, edgeSW, b2,
      WT3, hC16, as3, ad3, als3, ald3, N);
  // final aggregate (gather hC16) -> fp32 output
  aggregate1_kernel<<<aggGrid, 256, 0, stream>>>(hC16, als3, ald3, offsets, edgeSW,
                                                 b3, (float*)d_out, N);
}